// Round 1
// 269.384 us; speedup vs baseline: 1.0677x; 1.0677x over previous
//
#include <hip/hip_runtime.h>
#include <hip/hip_bf16.h>
#include <math.h>

// Problem constants
#define BPART   524288
#define NBLK    (BPART / 128)  // 4096
#define W7_OFF  98304          // 6 * 16384 bf16
#define WB_N    102400         // + 32*128 (padded W7t), bf16 count
#define BIAS_N  800            // 6*128 + 32 floats
#define PREP_N  (WB_N + BIAS_N)

typedef __bf16 bf16x8 __attribute__((ext_vector_type(8)));
typedef float  f32x16 __attribute__((ext_vector_type(16)));
typedef float  f32x4  __attribute__((ext_vector_type(4)));
typedef float  f32x2  __attribute__((ext_vector_type(2)));

#define MFMA __builtin_amdgcn_mfma_f32_32x32x16_bf16
#define UNROLL _Pragma("unroll")

union XU { unsigned u[4]; bf16x8 v; };

__device__ __forceinline__ unsigned short f2bf(float f) {
  union { float f; unsigned u; } v; v.f = f;
  unsigned r = v.u + 0x7fffu + ((v.u >> 16) & 1u);   // RNE
  return (unsigned short)(r >> 16);
}
// pack two fp32 -> bf16x2 (low16 = a, high16 = b) — verified earlier session
__device__ __forceinline__ unsigned pack_bf16(float a, float b) {
  unsigned ua = __builtin_bit_cast(unsigned, a) + 0x8000u;
  unsigned ub = __builtin_bit_cast(unsigned, b) + 0x8000u;
  return __builtin_amdgcn_perm(ub, ua, 0x07060302u);
}

// sigma: D-slot index -> real feature index. With weight rows (and biases)
// stored permuted by sigma, the MFMA D layout (n = 32tn+8q+4lk+j per lane)
// becomes, after pairwise bf16 packing, EXACTLY the next layer's B-fragment
// layout (k = 16t+8lk+4h+j, t=c>>1, h=c&1, c=4tn+q). Bijective bit shuffle:
// [tn1 tn0 q1 q0 | lk | j1 j0] -> [c3 c2 c1 | lk | c0 | j1 j0]
__device__ __forceinline__ int sigma(int n) {
  int c = ((n >> 5) << 2) | ((n >> 3) & 3);
  return ((c >> 1) << 4) | (((n >> 2) & 1) << 3) | ((c & 1) << 2) | (n & 3);
}

// packed fp32 VALU (VOP3P)
__device__ __forceinline__ f32x2 pk_mul(f32x2 a, f32x2 b) {
  f32x2 d; asm("v_pk_mul_f32 %0, %1, %2" : "=v"(d) : "v"(a), "v"(b)); return d;
}
__device__ __forceinline__ f32x2 pk_fma(f32x2 a, f32x2 b, f32x2 c) {
  f32x2 d; asm("v_pk_fma_f32 %0, %1, %2, %3" : "=v"(d) : "v"(a), "v"(b), "v"(c)); return d;
}
// tanh-form GELU on a pair; poly part packed, transcendentals scalar
__device__ __forceinline__ f32x2 gelu2(f32x2 z) {
  const f32x2 c1 = {0.1029432f, 0.1029432f};
  const f32x2 c0 = {2.30220818f, 2.30220818f};
  f32x2 z2 = pk_mul(z, z);
  f32x2 t  = pk_fma(z2, c1, c0);
  f32x2 yp = pk_mul(z, t);
  float e0 = __builtin_amdgcn_exp2f(-yp.x);
  float e1 = __builtin_amdgcn_exp2f(-yp.y);
  float r0 = __builtin_amdgcn_rcpf(e0 + 1.0f);
  float r1 = __builtin_amdgcn_rcpf(e1 + 1.0f);
  f32x2 g; g.x = z.x * r0; g.y = z.y * r1;
  return g;
}
// async 16B global->LDS (lane-linear dest)
__device__ __forceinline__ void cp16(const void* g, void* l) {
  __builtin_amdgcn_global_load_lds(
      (const __attribute__((address_space(1))) void*)g,
      (__attribute__((address_space(3))) void*)l, 16, 0, 0);
}

// ---- prep: cast+transpose fp32 weights into d_ws as the EXACT swizzled
// LDS image, with rows sigma-permuted (see sigma()). Biases permuted too. ----
__global__ void prep_weights(
    const float* __restrict__ W1, const float* __restrict__ W2,
    const float* __restrict__ W3, const float* __restrict__ W4,
    const float* __restrict__ W5, const float* __restrict__ W6,
    const float* __restrict__ W7,
    const float* __restrict__ b1, const float* __restrict__ b2,
    const float* __restrict__ b3, const float* __restrict__ b4,
    const float* __restrict__ b5, const float* __restrict__ b6,
    const float* __restrict__ b7,
    unsigned short* __restrict__ wsb, float* __restrict__ wsf)
{
  int idx = blockIdx.x * 256 + threadIdx.x;
  if (idx < WB_N) {
    unsigned short v = 0;
    if (idx < W7_OFF) {                     // W1..W6: Wt[sigma(n)][k] swizzled
      int l = idx >> 14;
      int o = idx & 16383;
      int n = o >> 7, e = o & 127;
      int k = (((e >> 3) ^ (n & 7)) << 3) | (e & 7);
      int sn = sigma(n);
      const float* W = (l==0)?W1:(l==1)?W2:(l==2)?W3:(l==3)?W4:(l==4)?W5:W6;
      float x = (l == 0) ? ((k < 89) ? W[k*128 + sn] : 0.0f)   // K-pad 89->128
                         : W[k*128 + sn];
      v = f2bf(x);
    } else {                                // W7t padded to 32 rows, swizzled
      int o = idx - W7_OFF;
      int n = o >> 7, e = o & 127;
      int k = (((e >> 3) ^ (n & 7)) << 3) | (e & 7);
      int sn = sigma(n);
      v = (sn < 9) ? f2bf(W7[k*9 + sn]) : (unsigned short)0;
    }
    wsb[idx] = v;
  } else if (idx < PREP_N) {                // biases, fp32, sigma-permuted
    int r = idx - WB_N;
    float x;
    if (r < 768) {
      int l = r >> 7, n = r & 127;
      const float* bb = (l==0)?b1:(l==1)?b2:(l==2)?b3:(l==3)?b4:(l==4)?b5:b6;
      x = bb[sigma(n)];
    } else {
      int n = r - 768;
      int sn = sigma(n);
      x = (sn < 9) ? b7[sn] : 0.0f;
    }
    wsf[r] = x;
  }
}

// Per-layer MFMA block: wave owns 32 particles (lane&31) x all 128 out-feats.
// acc[tn] n-tile tn covers D rows 32tn..32tn+31. Bias rides in as C at kk==0
// (read from the 512B LDS bias appendix; 2 distinct addrs/wave = broadcast).
#define MFMA_LAYER(NKK)                                                       \
  {                                                                           \
    const float* bls_ = (const float*)((const char*)wt_s + 32768);            \
    UNROLL                                                                    \
    for (int kk = 0; kk < (NKK); ++kk) {                                      \
      XU x_;                                                                  \
      x_.u[0] = xw[4*kk+0]; x_.u[1] = xw[4*kk+1];                             \
      x_.u[2] = xw[4*kk+2]; x_.u[3] = xw[4*kk+3];                             \
      const int ch_ = ((2*kk + lk) ^ x7) << 3;                                \
      UNROLL                                                                  \
      for (int tn = 0; tn < 4; ++tn) {                                        \
        bf16x8 w_ = *(const bf16x8*)&wt_s[tn*4096 + rb0 + ch_];               \
        if (kk == 0) {                                                        \
          f32x16 cf_;                                                         \
          UNROLL                                                              \
          for (int qq = 0; qq < 4; ++qq) {                                    \
            f32x4 b4_ = *(const f32x4*)&bls_[tn*32 + qq*8 + lk*4];            \
            cf_[4*qq+0] = b4_[0]; cf_[4*qq+1] = b4_[1];                       \
            cf_[4*qq+2] = b4_[2]; cf_[4*qq+3] = b4_[3];                       \
          }                                                                   \
          acc[tn] = MFMA(w_, x_.v, cf_, 0, 0, 0);                             \
        } else {                                                              \
          acc[tn] = MFMA(w_, x_.v, acc[tn], 0, 0, 0);                         \
        }                                                                     \
      }                                                                       \
    }                                                                         \
  }

// GELU + pack: acc slots (pairs within a (tn,q) combo c) -> next-layer B words.
// xw[4t + 2h + {0,1}] with t=c>>1, h=c&1; frag(kk=t) = xw[4t..4t+3].
#define GELU_EPILOGUE                                                         \
  UNROLL                                                                      \
  for (int c = 0; c < 16; ++c) {                                              \
    const int tn_ = c >> 2, q_ = c & 3, t_ = c >> 1, h_ = c & 1;              \
    f32x2 za_, zb_;                                                           \
    za_.x = acc[tn_][4*q_+0]; za_.y = acc[tn_][4*q_+1];                       \
    zb_.x = acc[tn_][4*q_+2]; zb_.y = acc[tn_][4*q_+3];                       \
    f32x2 ga_ = gelu2(za_);                                                   \
    f32x2 gb_ = gelu2(zb_);                                                   \
    xw[4*t_ + 2*h_ + 0] = pack_bf16(ga_.x, ga_.y);                            \
    xw[4*t_ + 2*h_ + 1] = pack_bf16(gb_.x, gb_.y);                            \
  }

// ---- main fused kernel: features + 7-layer MLP + symmetrize ----
// Register-resident activations; LDS holds only one layer's weights (+bias).
__global__ __launch_bounds__(256, 4) void stress_mlp(
    const float* __restrict__ F, const float* __restrict__ Cmat,
    const int* __restrict__ traj, const float* __restrict__ latent,
    const unsigned short* __restrict__ wst, const float* __restrict__ wsf,
    float* __restrict__ out)
{
  __shared__ __align__(16) unsigned short wt_s[128 * 128 + 256];  // 32KB + 512B bias

  const int tid  = threadIdx.x;
  const int lane = tid & 63;
  const int wid  = tid >> 6;
  const int lm   = lane & 31;
  const int lk   = lane >> 5;                 // k-half / n-quad selector
  const int x7   = lm & 7;
  const int rb0  = lm << 7;
  const int pbase = (int)blockIdx.x << 7;
  const int p    = pbase + (wid << 5) + lm;   // both lane-halves: same particle

  // issue W1 + b1 staging immediately (async DMA, overlaps feature phase)
  {
    const char* src = (const char*)wst;
    char* dst = (char*)wt_s;
    UNROLL
    for (int i = 0; i < 8; ++i)
      cp16(src + i*4096 + tid*16, dst + i*4096 + tid*16);
    if (tid < 32) cp16((const char*)wsf + tid*16, dst + 32768 + tid*16);
  }

  unsigned xw[32];   // B-fragment words; layer 1 uses xw[0..23] (K=96)

  // ---------- features -> layer-1 B words, fully in registers ----------
  {
    const float* Fp = F + (size_t)p * 9;
    float f[9];
    UNROLL
    for (int i = 0; i < 9; ++i) f[i] = Fp[i];
    float fft[9];
    UNROLL
    for (int i = 0; i < 3; ++i)
      UNROLL
      for (int k = 0; k < 3; ++k)
        fft[i*3+k] = f[i*3]*f[k*3] + f[i*3+1]*f[k*3+1] + f[i*3+2]*f[k*3+2];
    const float* lat = latent + (size_t)traj[0] * 64;

    if (lk == 0) {
      // octets 0,2,4,6,8,10: k = {0-7,16-23,32-39,48-55,64-71,80-87}
      xw[0] = pack_bf16(fft[0], fft[1]);
      xw[1] = pack_bf16(fft[2], fft[3]);
      xw[2] = pack_bf16(fft[4], fft[5]);
      xw[3] = pack_bf16(fft[6], fft[7]);
      const float* Cp = Cmat + (size_t)p * 9;
      UNROLL
      for (int i = 0; i < 4; ++i) xw[4+i] = pack_bf16(Cp[2*i], Cp[2*i+1]);
      UNROLL
      for (int t = 0; t < 4; ++t) {          // lat[7+16t .. 14+16t]
        const float* lb = lat + 7 + 16*t;
        UNROLL
        for (int i = 0; i < 4; ++i) xw[8 + 4*t + i] = pack_bf16(lb[2*i], lb[2*i+1]);
      }
    } else {
      // octets 1,3,5,7,9,11: k = {8-15,24-31,40-47,56-63,72-79,88-95}
      float det = f[0]*(f[4]*f[8]-f[5]*f[7]) - f[1]*(f[3]*f[8]-f[5]*f[6])
                + f[2]*(f[3]*f[7]-f[4]*f[6]);
      float J  = fmaxf(det, 1e-6f);
      float J1 = fmaxf(f[0], 1e-6f);
      // singular values = sqrt(eig(F F^T)); analytic symmetric 3x3 eigensolve
      float a00=fft[0], a01=fft[1], a02=fft[2], a11=fft[4], a12=fft[5], a22=fft[8];
      float q  = (a00+a11+a22) * (1.0f/3.0f);
      float d0 = a00-q, d1 = a11-q, d2 = a22-q;
      float p2 = d0*d0 + d1*d1 + d2*d2 + 2.0f*(a01*a01 + a02*a02 + a12*a12);
      float e0, e1, e2;
      if (p2 < 1e-14f) { e0 = e1 = e2 = q; }
      else {
        float pp  = sqrtf(p2 * (1.0f/6.0f));
        float inv = 1.0f / pp;
        float b00=d0*inv, b11=d1*inv, b22=d2*inv, b01=a01*inv, b02=a02*inv, b12=a12*inv;
        float detb = b00*(b11*b22-b12*b12) - b01*(b01*b22-b12*b02) + b02*(b01*b12-b11*b02);
        float rr = 0.5f * detb;
        rr = fminf(fmaxf(rr, -1.0f), 1.0f);
        float pr = acosf(rr) * (1.0f / (3.0f * 6.2831853071795864f));  // revolutions
        e0 = q + 2.0f*pp*__builtin_amdgcn_cosf(pr);
        e2 = q + 2.0f*pp*__builtin_amdgcn_cosf(pr + (1.0f/3.0f));
        e1 = 3.0f*q - e0 - e2;
      }
      float s0 = sqrtf(fmaxf(e0, 0.f));
      float s1 = sqrtf(fmaxf(e1, 0.f));
      float s2 = sqrtf(fmaxf(e2, 0.f));
      xw[0] = pack_bf16(fft[8], logf(J));
      xw[1] = pack_bf16(s0, s1);
      xw[2] = pack_bf16(s2, J);
      xw[3] = pack_bf16(logf(J1), J1);
      float c8 = Cmat[(size_t)p*9 + 8];
      xw[4] = pack_bf16(c8, lat[0]);
      xw[5] = pack_bf16(lat[1], lat[2]);
      xw[6] = pack_bf16(lat[3], lat[4]);
      xw[7] = pack_bf16(lat[5], lat[6]);
      UNROLL
      for (int t = 0; t < 3; ++t) {          // lat[15+16t .. 22+16t]
        const float* lb = lat + 15 + 16*t;
        UNROLL
        for (int i = 0; i < 4; ++i) xw[8 + 4*t + i] = pack_bf16(lb[2*i], lb[2*i+1]);
      }
      xw[20] = pack_bf16(lat[63], 0.0f);     // k88, k89=0
      xw[21] = 0u; xw[22] = 0u; xw[23] = 0u; // k90-95 = 0
    }
  }

  f32x16 acc[4];

  // ---------- layer 1 (K=96) ----------
  __syncthreads();            // W1+b1 staged; drains cp16 vmcnt
  MFMA_LAYER(6)
  __syncthreads();            // wt_s reads done
  {                           // stage W2 + b2
    const char* src = (const char*)(wst + (1 << 14));
    UNROLL
    for (int i = 0; i < 8; ++i)
      cp16(src + i*4096 + tid*16, (char*)wt_s + i*4096 + tid*16);
    if (tid < 32) cp16((const char*)(wsf + 128) + tid*16, (char*)wt_s + 32768 + tid*16);
  }
  GELU_EPILOGUE

  // ---------- layers 2..6 ----------
  for (int l = 1; l < 6; ++l) {
    __syncthreads();
    MFMA_LAYER(8)
    __syncthreads();
    if (l < 5) {              // stage W(l+2) + b(l+2)
      const char* src = (const char*)(wst + ((l + 1) << 14));
      UNROLL
      for (int i = 0; i < 8; ++i)
        cp16(src + i*4096 + tid*16, (char*)wt_s + i*4096 + tid*16);
      if (tid < 32)
        cp16((const char*)(wsf + ((l + 1) << 7)) + tid*16, (char*)wt_s + 32768 + tid*16);
    } else {                  // stage W7 (8KB) + b7 (128B)
      const char* src = (const char*)(wst + W7_OFF);
      UNROLL
      for (int i = 0; i < 2; ++i)
        cp16(src + i*4096 + tid*16, (char*)wt_s + i*4096 + tid*16);
      if (tid < 8)
        cp16((const char*)(wsf + 768) + tid*16, (char*)wt_s + 32768 + tid*16);
    }
    GELU_EPILOGUE
  }

  // ---------- layer 7 (128 -> 9, no activation) + symmetrize ----------
  __syncthreads();            // W7+b7 staged
  f32x16 a7;
  {
    const float* bls = (const float*)((const char*)wt_s + 32768);
    UNROLL
    for (int kk = 0; kk < 8; ++kk) {
      XU x;
      x.u[0] = xw[4*kk+0]; x.u[1] = xw[4*kk+1];
      x.u[2] = xw[4*kk+2]; x.u[3] = xw[4*kk+3];
      const int ch = ((2*kk + lk) ^ x7) << 3;
      bf16x8 w = *(const bf16x8*)&wt_s[rb0 + ch];
      if (kk == 0) {
        f32x16 cf;
        UNROLL
        for (int qq = 0; qq < 4; ++qq) {
          f32x4 b4 = *(const f32x4*)&bls[qq*8 + lk*4];
          cf[4*qq+0] = b4[0]; cf[4*qq+1] = b4[1];
          cf[4*qq+2] = b4[2]; cf[4*qq+3] = b4[3];
        }
        a7 = MFMA(w, x.v, cf, 0, 0, 0);
      } else {
        a7 = MFMA(w, x.v, a7, 0, 0, 0);
      }
    }
  }
  __syncthreads();            // wt_s reads done; reuse as fp32 output scratch

  // slot->real output (sigma): lower lanes hold o0..o7 in regs 0..7,
  // o8 sits in upper-lane reg 0 -> one cross-half shuffle.
  float o8 = __shfl_xor(a7[0], 32);
  float* ots = (float*)wt_s;  // [128][9] fp32
  if (lk == 0) {
    const int row = (wid << 5) + lm;
    float z[9];
    UNROLL
    for (int i = 0; i < 8; ++i) z[i] = a7[i];
    z[8] = o8;
    UNROLL
    for (int rr = 0; rr < 3; ++rr)
      UNROLL
      for (int cc = 0; cc < 3; ++cc)
        ots[row*9 + rr*3 + cc] = 0.5f * (z[rr*3+cc] + z[cc*3+rr]);
  }
  __syncthreads();

  float4* dst = (float4*)(out + (size_t)pbase * 9);   // 4608 B, 16B-aligned
  const float4* srcv = (const float4*)ots;
  for (int s = tid; s < 288; s += 256) dst[s] = srcv[s];
}

extern "C" void kernel_launch(void* const* d_in, const int* in_sizes, int n_in,
                              void* d_out, int out_size, void* d_ws, size_t ws_size,
                              hipStream_t stream) {
  const float* F   = (const float*)d_in[0];
  const float* C   = (const float*)d_in[1];
  const int*   trj = (const int*)d_in[2];
  const float* lat = (const float*)d_in[3];
  const float* W1  = (const float*)d_in[4];
  const float* b1  = (const float*)d_in[5];
  const float* W2  = (const float*)d_in[6];
  const float* b2  = (const float*)d_in[7];
  const float* W3  = (const float*)d_in[8];
  const float* b3  = (const float*)d_in[9];
  const float* W4  = (const float*)d_in[10];
  const float* b4  = (const float*)d_in[11];
  const float* W5  = (const float*)d_in[12];
  const float* b5  = (const float*)d_in[13];
  const float* W6  = (const float*)d_in[14];
  const float* b6  = (const float*)d_in[15];
  const float* W7  = (const float*)d_in[16];
  const float* b7  = (const float*)d_in[17];

  unsigned short* wsb = (unsigned short*)d_ws;           // bf16 swizzled Wt image
  float* wsf = (float*)((char*)d_ws + WB_N * 2);         // fp32 biases (16B-aligned)

  prep_weights<<<dim3((PREP_N + 255) / 256), dim3(256), 0, stream>>>(
      W1, W2, W3, W4, W5, W6, W7, b1, b2, b3, b4, b5, b6, b7, wsb, wsf);
  stress_mlp<<<dim3(NBLK), dim3(256), 0, stream>>>(
      F, C, trj, lat, wsb, wsf, (float*)d_out);
}